// Round 1
// baseline (1561.572 us; speedup 1.0000x reference)
//
#include <hip/hip_runtime.h>
#include <math.h>

#define NHEAD 16
#define HEAD_DIM 64
#define D_MODEL 1024
#define T_SEQ 2048

// ---------------- GEMM: C = A @ W^T + bias ----------------
// A: [M][K] row-major, W: [N][K] row-major (torch Linear weight), bias: [N]
// head_layout=1: scatter C into [B][NHEAD][T][HEAD_DIM] (m=b*T+t, n=h*64+d)
constexpr int BM = 64, BN = 64, BK = 16;

__global__ __launch_bounds__(256)
void gemm_xwt(const float* __restrict__ A, const float* __restrict__ W,
              const float* __restrict__ bias, float* __restrict__ C,
              int M, int N, int K, int head_layout) {
  __shared__ float As[BK][BM + 4];   // transposed: As[k][m], row stride 68 (16B aligned)
  __shared__ float Ws[BK][BN + 4];   // Ws[k][n]
  const int tid = threadIdx.x;
  const int tm = tid & 15;           // micro-tile m index
  const int tn = tid >> 4;           // micro-tile n index
  const int row0 = blockIdx.y * BM;
  const int col0 = blockIdx.x * BN;
  const int r  = tid >> 2;           // 0..63  (staging row)
  const int c4 = (tid & 3) * 4;      // 0,4,8,12 (staging col, float4)
  float acc[4][4] = {};

  for (int k0 = 0; k0 < K; k0 += BK) {
    float4 av = *(const float4*)&A[(size_t)(row0 + r) * K + k0 + c4];
    float4 wv = *(const float4*)&W[(size_t)(col0 + r) * K + k0 + c4];
    __syncthreads();   // previous iteration's reads done before overwrite
    As[c4 + 0][r] = av.x; As[c4 + 1][r] = av.y;
    As[c4 + 2][r] = av.z; As[c4 + 3][r] = av.w;
    Ws[c4 + 0][r] = wv.x; Ws[c4 + 1][r] = wv.y;
    Ws[c4 + 2][r] = wv.z; Ws[c4 + 3][r] = wv.w;
    __syncthreads();
#pragma unroll
    for (int kk = 0; kk < BK; ++kk) {
      float4 a = *(const float4*)&As[kk][tm * 4];
      float4 b = *(const float4*)&Ws[kk][tn * 4];
      float aa[4] = {a.x, a.y, a.z, a.w};
      float bb[4] = {b.x, b.y, b.z, b.w};
#pragma unroll
      for (int i = 0; i < 4; ++i)
#pragma unroll
        for (int j = 0; j < 4; ++j) acc[i][j] += aa[i] * bb[j];
    }
  }

#pragma unroll
  for (int i = 0; i < 4; ++i) {
    int m = row0 + tm * 4 + i;
#pragma unroll
    for (int j = 0; j < 4; ++j) {
      int n = col0 + tn * 4 + j;
      float c = acc[i][j] + bias[n];
      if (head_layout) {
        int bb_ = m >> 11;            // T_SEQ = 2048
        int t   = m & (T_SEQ - 1);
        int h   = n >> 6;             // HEAD_DIM = 64
        int d   = n & 63;
        C[((((size_t)bb_ * NHEAD + h) * T_SEQ + t) << 6) + d] = c;
      } else {
        C[(size_t)m * N + n] = c;
      }
    }
  }
}

// ---------------- Flash attention (f32) ----------------
// Block: 256 threads = 32 q-rows x 8 lanes. One block per (b, h, 32-row q-tile).
constexpr int QB = 32, KB = 32;

__global__ __launch_bounds__(256)
void attn_fwd(const float* __restrict__ Qh, const float* __restrict__ Kh,
              const float* __restrict__ Vh, const float* __restrict__ amask,
              const unsigned char* __restrict__ kpm, const float* __restrict__ sf,
              const float* __restrict__ alpha_p, float* __restrict__ O) {
  __shared__ float Ks[KB][68];       // pad 68: float4-aligned + conflict-spread
  __shared__ float Vs[KB][68];
  __shared__ float Ps[QB][33];
  const int b = blockIdx.z, h = blockIdx.y;
  const int q0 = blockIdx.x * QB;
  const int tid = threadIdx.x;
  const int row = tid >> 3;          // 0..31
  const int lane8 = tid & 7;         // 0..7
  const float alpha = *alpha_p;
  const float scale = 0.125f;        // HEAD_DIM^-0.5

  const float* Qbase = Qh + (((size_t)b * NHEAD + h) * T_SEQ + q0) * HEAD_DIM;
  const float* Kb    = Kh + (((size_t)b * NHEAD + h) * T_SEQ) * HEAD_DIM;
  const float* Vb    = Vh + (((size_t)b * NHEAD + h) * T_SEQ) * HEAD_DIM;

  float4 q[16];
#pragma unroll
  for (int i = 0; i < 16; ++i) q[i] = *(const float4*)&Qbase[row * HEAD_DIM + i * 4];

  float acc[8] = {};
  float mrow = -INFINITY, lrow = 0.f;
  const float sfq = sf[(size_t)b * T_SEQ + q0 + row];
  const float* amrow = amask + (size_t)(q0 + row) * T_SEQ;
  const float* sfk_b = sf + (size_t)b * T_SEQ;
  const unsigned char* kpm_b = kpm + (size_t)b * T_SEQ;

  for (int k0 = 0; k0 < T_SEQ; k0 += KB) {
    __syncthreads();   // previous tile's PV reads done before restaging
    for (int i = tid; i < KB * 16; i += 256) {
      int rr = i >> 4, cc = (i & 15) * 4;
      *(float4*)&Ks[rr][cc] = *(const float4*)&Kb[(size_t)(k0 + rr) * HEAD_DIM + cc];
      *(float4*)&Vs[rr][cc] = *(const float4*)&Vb[(size_t)(k0 + rr) * HEAD_DIM + cc];
    }
    __syncthreads();

    // --- scores: each lane computes 4 keys (stride 8 -> conflict-free Ks reads)
    float s[4];
#pragma unroll
    for (int j = 0; j < 4; ++j) {
      int kk = lane8 + 8 * j;
      float4 dot = make_float4(0.f, 0.f, 0.f, 0.f);
#pragma unroll
      for (int d4 = 0; d4 < 16; ++d4) {
        float4 kv = *(const float4*)&Ks[kk][d4 * 4];
        dot.x += q[d4].x * kv.x; dot.y += q[d4].y * kv.y;
        dot.z += q[d4].z * kv.z; dot.w += q[d4].w * kv.w;
      }
      float dd = (dot.x + dot.y) + (dot.z + dot.w);
      float df = sfq - sfk_b[k0 + kk];
      float bias = alpha * copysignf(log1pf(fabsf(df)), df);
      float sc = dd * scale + bias + amrow[k0 + kk];
      if (kpm_b[k0 + kk]) sc = -INFINITY;
      s[j] = sc;
    }

    // --- online softmax (8-lane group reductions)
    float tmax = fmaxf(fmaxf(s[0], s[1]), fmaxf(s[2], s[3]));
#pragma unroll
    for (int off = 1; off < 8; off <<= 1) tmax = fmaxf(tmax, __shfl_xor(tmax, off));
    float mnew = fmaxf(mrow, tmax);
    float corr = __expf(mrow - mnew);
    float p[4], psum = 0.f;
#pragma unroll
    for (int j = 0; j < 4; ++j) { p[j] = __expf(s[j] - mnew); psum += p[j]; }
#pragma unroll
    for (int off = 1; off < 8; off <<= 1) psum += __shfl_xor(psum, off);
    lrow = lrow * corr + psum;
    mrow = mnew;
#pragma unroll
    for (int i = 0; i < 8; ++i) acc[i] *= corr;
#pragma unroll
    for (int j = 0; j < 4; ++j) Ps[row][lane8 + 8 * j] = p[j];
    __syncthreads();

    // --- PV: acc[d] += sum_k p[k] * V[k][d]; lane owns 8 dims
#pragma unroll
    for (int kk2 = 0; kk2 < KB; ++kk2) {
      float pp = Ps[row][kk2];
      float4 v0 = *(const float4*)&Vs[kk2][lane8 * 8];
      float4 v1 = *(const float4*)&Vs[kk2][lane8 * 8 + 4];
      acc[0] += pp * v0.x; acc[1] += pp * v0.y; acc[2] += pp * v0.z; acc[3] += pp * v0.w;
      acc[4] += pp * v1.x; acc[5] += pp * v1.y; acc[6] += pp * v1.z; acc[7] += pp * v1.w;
    }
  }

  float inv = 1.f / lrow;
  float4 o0 = make_float4(acc[0] * inv, acc[1] * inv, acc[2] * inv, acc[3] * inv);
  float4 o1 = make_float4(acc[4] * inv, acc[5] * inv, acc[6] * inv, acc[7] * inv);
  float4* op = (float4*)&O[((size_t)b * T_SEQ + q0 + row) * D_MODEL + h * HEAD_DIM + lane8 * 8];
  op[0] = o0;
  op[1] = o1;
}

extern "C" void kernel_launch(void* const* d_in, const int* in_sizes, int n_in,
                              void* d_out, int out_size, void* d_ws, size_t ws_size,
                              hipStream_t stream) {
  const float* query = (const float*)d_in[0];
  const float* key   = (const float*)d_in[1];
  const float* value = (const float*)d_in[2];
  const unsigned char* kpm = (const unsigned char*)d_in[3];
  const float* amask = (const float*)d_in[4];
  const float* sf    = (const float*)d_in[5];
  const float* Wq = (const float*)d_in[6];
  const float* bq = (const float*)d_in[7];
  const float* Wk = (const float*)d_in[8];
  const float* bk = (const float*)d_in[9];
  const float* Wv = (const float*)d_in[10];
  const float* bv = (const float*)d_in[11];
  const float* Wo = (const float*)d_in[12];
  const float* bo = (const float*)d_in[13];
  const float* alpha = (const float*)d_in[14];
  float* out = (float*)d_out;
  float* ws  = (float*)d_ws;

  const int M = 2 * T_SEQ;  // B*T = 4096
  float* Qh = ws;
  float* Kh = ws + (size_t)M * D_MODEL;
  float* Vh = ws + 2 * (size_t)M * D_MODEL;
  float* Oh = ws + 3 * (size_t)M * D_MODEL;

  dim3 gg(D_MODEL / BN, M / BM);   // (16, 64)
  gemm_xwt<<<gg, 256, 0, stream>>>(query, Wq, bq, Qh, M, D_MODEL, D_MODEL, 1);
  gemm_xwt<<<gg, 256, 0, stream>>>(key,   Wk, bk, Kh, M, D_MODEL, D_MODEL, 1);
  gemm_xwt<<<gg, 256, 0, stream>>>(value, Wv, bv, Vh, M, D_MODEL, D_MODEL, 1);

  dim3 ga(T_SEQ / QB, NHEAD, 2);   // (64, 16, 2)
  attn_fwd<<<ga, 256, 0, stream>>>(Qh, Kh, Vh, amask, kpm, sf, alpha, Oh);

  gemm_xwt<<<gg, 256, 0, stream>>>(Oh, Wo, bo, out, M, D_MODEL, D_MODEL, 0);
}

// Round 2
// 525.717 us; speedup vs baseline: 2.9704x; 2.9704x over previous
//
#include <hip/hip_runtime.h>
#include <math.h>

typedef __bf16 bf16_t;
typedef __bf16 bf16x8 __attribute__((ext_vector_type(8)));
typedef float  f32x4  __attribute__((ext_vector_type(4)));

#define NHEAD 16
#define HDIM 64
#define DMODEL 1024
#define TSEQ 2048

__device__ __forceinline__ f32x4 mfma16(bf16x8 a, bf16x8 b, f32x4 c) {
  return __builtin_amdgcn_mfma_f32_16x16x32_bf16(a, b, c, 0, 0, 0);
}

// async global->LDS, 16B per lane; lds base must be wave-uniform (HW adds lane*16)
__device__ __forceinline__ void gload16(const bf16_t* g, bf16_t* l) {
  __builtin_amdgcn_global_load_lds((const __attribute__((address_space(1))) void*)g,
                                   (__attribute__((address_space(3))) void*)l, 16, 0, 0);
}

// pack two f32 -> (bf16(hi)<<16)|bf16(lo)
__device__ __forceinline__ unsigned pk2(float lo, float hi) {
  unsigned short a = __builtin_bit_cast(unsigned short, (__bf16)lo);
  unsigned short c = __builtin_bit_cast(unsigned short, (__bf16)hi);
  return ((unsigned)c << 16) | a;
}

// load 8 consecutive f32, split into hi/lo bf16x8, store to frag-major LDS slot
__device__ __forceinline__ void cvt8(const float* p, bf16_t* dh, bf16_t* dl, int slotoff) {
  f32x4 x0 = *(const f32x4*)p;
  f32x4 x1 = *(const f32x4*)(p + 4);
  bf16x8 hfr, lfr;
#pragma unroll
  for (int j = 0; j < 4; ++j) {
    float v = x0[j];
    __bf16 hb = (__bf16)v;
    hfr[j] = hb; lfr[j] = (__bf16)(v - (float)hb);
    float w = x1[j];
    __bf16 wb = (__bf16)w;
    hfr[4 + j] = wb; lfr[4 + j] = (__bf16)(w - (float)wb);
  }
  *(bf16x8*)(dh + slotoff) = hfr;
  *(bf16x8*)(dl + slotoff) = lfr;
}

// C = A @ W^T + bias via bf16x3 split MFMA. A:[M=4096][1024] f32, W:[N rows][1024] f32.
// MODE 0: f32 out [M][1024]   (O-projection -> d_out)
// MODE 1: bf16 hi/lo out, head layout [b][h][t][d]   (Q,K)
// MODE 2: swapped operands, bf16 hi/lo out transposed [b][h][d][t]   (V)
// tile 128(M) x 64(N), BK=32, 256 threads (4 waves, 2x2)
template<int MODE>
__global__ __launch_bounds__(256)
void gemm_mfma(const float* __restrict__ A, const float* __restrict__ W,
               const float* __restrict__ bias,
               bf16_t* __restrict__ obh, bf16_t* __restrict__ obl,
               float* __restrict__ of) {
  __shared__ bf16_t AH[8 * 512], AL[8 * 512], WH[4 * 512], WL[4 * 512];
  const int tid = threadIdx.x;
  const int lane = tid & 63;
  const int a15 = lane & 15, g = lane >> 4;
  const int wv = tid >> 6, wm = wv >> 1, wn = wv & 1;
  const int m0 = blockIdx.y * 128, n0 = blockIdx.x * 64;
  constexpr int NI = (MODE == 2) ? 2 : 4;
  constexpr int NJ = (MODE == 2) ? 4 : 2;
  f32x4 acc[NI][NJ] = {};

  for (int k0 = 0; k0 < DMODEL; k0 += 32) {
    __syncthreads();
    {
      // A: 512 slots (8 tiles of 16 rows); W: 256 slots (4 tiles)
      int s = tid;
      int tile = s >> 6, l = s & 63;
      const float* p = A + (size_t)(m0 + tile * 16 + (l & 15)) * DMODEL + k0 + 8 * (l >> 4);
      cvt8(p, AH, AL, s * 8);
      s = tid + 256;
      tile = s >> 6; l = s & 63;
      p = A + (size_t)(m0 + tile * 16 + (l & 15)) * DMODEL + k0 + 8 * (l >> 4);
      cvt8(p, AH, AL, s * 8);
      s = tid & 255;
      tile = s >> 6; l = s & 63;
      p = W + (size_t)(n0 + tile * 16 + (l & 15)) * DMODEL + k0 + 8 * (l >> 4);
      cvt8(p, WH, WL, s * 8);
    }
    __syncthreads();

    bf16x8 ah[4], al[4], wh[2], wl[2];
#pragma unroll
    for (int i = 0; i < 4; ++i) {
      ah[i] = *(const bf16x8*)&AH[(wm * 4 + i) * 512 + lane * 8];
      al[i] = *(const bf16x8*)&AL[(wm * 4 + i) * 512 + lane * 8];
    }
#pragma unroll
    for (int j = 0; j < 2; ++j) {
      wh[j] = *(const bf16x8*)&WH[(wn * 2 + j) * 512 + lane * 8];
      wl[j] = *(const bf16x8*)&WL[(wn * 2 + j) * 512 + lane * 8];
    }
    if (MODE == 2) {
#pragma unroll
      for (int i = 0; i < 2; ++i)
#pragma unroll
        for (int j = 0; j < 4; ++j) {
          acc[i][j] = mfma16(wh[i], ah[j], acc[i][j]);
          acc[i][j] = mfma16(wh[i], al[j], acc[i][j]);
          acc[i][j] = mfma16(wl[i], ah[j], acc[i][j]);
        }
    } else {
#pragma unroll
      for (int i = 0; i < 4; ++i)
#pragma unroll
        for (int j = 0; j < 2; ++j) {
          acc[i][j] = mfma16(ah[i], wh[j], acc[i][j]);
          acc[i][j] = mfma16(ah[i], wl[j], acc[i][j]);
          acc[i][j] = mfma16(al[i], wh[j], acc[i][j]);
        }
    }
  }

  if (MODE == 0) {
#pragma unroll
    for (int i = 0; i < 4; ++i)
#pragma unroll
      for (int j = 0; j < 2; ++j) {
        int n = n0 + wn * 32 + j * 16 + a15;
        float bs = bias[n];
#pragma unroll
        for (int r = 0; r < 4; ++r) {
          int m = m0 + wm * 64 + i * 16 + 4 * g + r;
          of[(size_t)m * DMODEL + n] = acc[i][j][r] + bs;
        }
      }
  } else if (MODE == 1) {
#pragma unroll
    for (int i = 0; i < 4; ++i)
#pragma unroll
      for (int j = 0; j < 2; ++j) {
        int n = n0 + wn * 32 + j * 16 + a15;
        float bs = bias[n];
        int hh = n >> 6, d = n & 63;
#pragma unroll
        for (int r = 0; r < 4; ++r) {
          int m = m0 + wm * 64 + i * 16 + 4 * g + r;
          int bb = m >> 11, t = m & (TSEQ - 1);
          float v = acc[i][j][r] + bs;
          size_t o = (((size_t)(bb * NHEAD + hh)) * TSEQ + t) * HDIM + d;
          __bf16 hb = (__bf16)v;
          obh[o] = hb;
          obl[o] = (__bf16)(v - (float)hb);
        }
      }
  } else {
#pragma unroll
    for (int i = 0; i < 2; ++i)
#pragma unroll
      for (int j = 0; j < 4; ++j) {
        int m = m0 + wm * 64 + j * 16 + a15;
        int bb = m >> 11, t = m & (TSEQ - 1);
#pragma unroll
        for (int r = 0; r < 4; ++r) {
          int n = n0 + wn * 32 + i * 16 + 4 * g + r;
          float v = acc[i][j][r] + bias[n];
          int hh = n >> 6, d = n & 63;
          size_t o = (((size_t)(bb * NHEAD + hh)) * HDIM + d) * TSEQ + t;
          __bf16 hb = (__bf16)v;
          obh[o] = hb;
          obl[o] = (__bf16)(v - (float)hb);
        }
      }
  }
}

// Flash attention, MFMA. Block = 256 thr (4 waves); each wave owns 16 q-rows.
// K-tile = 64 keys. S^T = mfma(K, Q) (3-way split), softmax in-register,
// P redistributed via shfl, O^T = mfma(Vt, P) with V pre-transposed hi/lo.
__global__ __launch_bounds__(256)
void attn_mfma(const bf16_t* __restrict__ Qhi, const bf16_t* __restrict__ Qlo,
               const bf16_t* __restrict__ Khi, const bf16_t* __restrict__ Klo,
               const bf16_t* __restrict__ Vth, const bf16_t* __restrict__ Vtl,
               const float* __restrict__ amask, const unsigned char* __restrict__ kpm,
               const float* __restrict__ sf, const float* __restrict__ alpha_p,
               float* __restrict__ O) {
  __shared__ bf16_t KH[8 * 512], KL[8 * 512], VH[8 * 512], VL[8 * 512];
  const int tid = threadIdx.x;
  const int lane = tid & 63, wv = tid >> 6;
  const int a15 = lane & 15, g = lane >> 4;
  const int b = blockIdx.z, h = blockIdx.y, q0 = blockIdx.x * 64;
  const int bh = b * NHEAD + h;
  const int qg = q0 + wv * 16 + a15;
  const float alpha = *alpha_p;

  const bf16_t* Qh_b = Qhi + ((size_t)bh * TSEQ + qg) * HDIM;
  const bf16_t* Ql_b = Qlo + ((size_t)bh * TSEQ + qg) * HDIM;
  const bf16_t* Kh_b = Khi + (size_t)bh * TSEQ * HDIM;
  const bf16_t* Kl_b = Klo + (size_t)bh * TSEQ * HDIM;
  const bf16_t* Vh_b = Vth + (size_t)bh * HDIM * TSEQ;
  const bf16_t* Vl_b = Vtl + (size_t)bh * HDIM * TSEQ;
  const float* amrow = amask + (size_t)qg * TSEQ;
  const float* sf_b = sf + (size_t)b * TSEQ;
  const unsigned char* kpm_b = kpm + (size_t)b * TSEQ;
  const float sfq = sf_b[qg];

  bf16x8 qh[2], ql[2];
  qh[0] = *(const bf16x8*)&Qh_b[8 * g];
  qh[1] = *(const bf16x8*)&Qh_b[32 + 8 * g];
  ql[0] = *(const bf16x8*)&Ql_b[8 * g];
  ql[1] = *(const bf16x8*)&Ql_b[32 + 8 * g];

  f32x4 aco[4] = {};
  float m_run = -3.0e38f, l_run = 0.f;

  for (int k0 = 0; k0 < TSEQ; k0 += 64) {
    __syncthreads();
#pragma unroll
    for (int c = 0; c < 2; ++c) {
      int sb = wv * 2 + c;
      int ts = sb >> 1, ks = sb & 1;
      size_t ko = (size_t)(k0 + 16 * ts + a15) * HDIM + 32 * ks + 8 * g;
      gload16(Kh_b + ko, &KH[sb * 512]);
      gload16(Kl_b + ko, &KL[sb * 512]);
      size_t vo = (size_t)(16 * ts + a15) * TSEQ + k0 + 32 * ks + 8 * g;
      gload16(Vh_b + vo, &VH[sb * 512]);
      gload16(Vl_b + vo, &VL[sb * 512]);
    }
    __syncthreads();

    // S^T frags: D[key][q], 4 key-subtiles of 16
    f32x4 s4[4];
#pragma unroll
    for (int mt = 0; mt < 4; ++mt) {
      bf16x8 k0h = *(const bf16x8*)&KH[(mt * 2 + 0) * 512 + lane * 8];
      bf16x8 k1h = *(const bf16x8*)&KH[(mt * 2 + 1) * 512 + lane * 8];
      bf16x8 k0l = *(const bf16x8*)&KL[(mt * 2 + 0) * 512 + lane * 8];
      bf16x8 k1l = *(const bf16x8*)&KL[(mt * 2 + 1) * 512 + lane * 8];
      f32x4 sa = {};
      sa = mfma16(k0h, qh[0], sa);
      sa = mfma16(k1h, qh[1], sa);
      sa = mfma16(k0h, ql[0], sa);
      sa = mfma16(k1h, ql[1], sa);
      sa = mfma16(k0l, qh[0], sa);
      sa = mfma16(k1l, qh[1], sa);
      s4[mt] = sa;
    }

    // scores: scale + stoich bias + mask; lane's q = a15, keys = 16mt+4g+r
#pragma unroll
    for (int mt = 0; mt < 4; ++mt) {
      int kb = k0 + 16 * mt + 4 * g;
      f32x4 sfk = *(const f32x4*)&sf_b[kb];
      f32x4 am = *(const f32x4*)&amrow[kb];
      unsigned kp = *(const unsigned*)&kpm_b[kb];
#pragma unroll
      for (int r = 0; r < 4; ++r) {
        float df = sfq - sfk[r];
        float bs = alpha * copysignf(__logf(1.0f + fabsf(df)), df);
        float sc = s4[mt][r] * 0.125f + bs + am[r];
        if ((kp >> (8 * r)) & 0xff) sc = -1.0e30f;
        s4[mt][r] = sc;
      }
    }

    // online softmax (row = q = a15; partials across lane groups via xor 16,32)
    float tmax = -3.0e38f;
#pragma unroll
    for (int mt = 0; mt < 4; ++mt)
#pragma unroll
      for (int r = 0; r < 4; ++r) tmax = fmaxf(tmax, s4[mt][r]);
    tmax = fmaxf(tmax, __shfl_xor(tmax, 16));
    tmax = fmaxf(tmax, __shfl_xor(tmax, 32));
    float mnew = fmaxf(m_run, tmax);
    float corr = __expf(m_run - mnew);
    float psum = 0.f;
    unsigned pk01[4], pk23[4];
#pragma unroll
    for (int mt = 0; mt < 4; ++mt) {
      float p0 = __expf(s4[mt][0] - mnew);
      float p1 = __expf(s4[mt][1] - mnew);
      float p2 = __expf(s4[mt][2] - mnew);
      float p3 = __expf(s4[mt][3] - mnew);
      psum += (p0 + p1) + (p2 + p3);
      pk01[mt] = pk2(p0, p1);
      pk23[mt] = pk2(p2, p3);
    }
    psum += __shfl_xor(psum, 16);
    psum += __shfl_xor(psum, 32);
    l_run = l_run * corr + psum;
    m_run = mnew;
#pragma unroll
    for (int dt = 0; dt < 4; ++dt) aco[dt] *= corr;

    // P -> B-frag layout: slot (g,j) must hold key 32ks+8g+j of row q=a15
    bf16x8 pf[2];
#pragma unroll
    for (int ks = 0; ks < 2; ++ks) {
      int src0 = a15 + 16 * (2 * (g & 1));
      int src1 = src0 + 16;
      unsigned A0 = __shfl(pk01[2 * ks + 0], src0), A1 = __shfl(pk01[2 * ks + 1], src0);
      unsigned B0 = __shfl(pk23[2 * ks + 0], src0), B1 = __shfl(pk23[2 * ks + 1], src0);
      unsigned C0 = __shfl(pk01[2 * ks + 0], src1), C1 = __shfl(pk01[2 * ks + 1], src1);
      unsigned D0 = __shfl(pk23[2 * ks + 0], src1), D1 = __shfl(pk23[2 * ks + 1], src1);
      bool hi2 = (g >> 1) & 1;
      uint4 wds;
      wds.x = hi2 ? A1 : A0;
      wds.y = hi2 ? B1 : B0;
      wds.z = hi2 ? C1 : C0;
      wds.w = hi2 ? D1 : D0;
      pf[ks] = __builtin_bit_cast(bf16x8, wds);
    }

    // O^T += Vt * P  (V split hi/lo)
#pragma unroll
    for (int dt = 0; dt < 4; ++dt) {
#pragma unroll
      for (int ks = 0; ks < 2; ++ks) {
        bf16x8 vh = *(const bf16x8*)&VH[(dt * 2 + ks) * 512 + lane * 8];
        bf16x8 vl = *(const bf16x8*)&VL[(dt * 2 + ks) * 512 + lane * 8];
        aco[dt] = mfma16(vh, pf[ks], aco[dt]);
        aco[dt] = mfma16(vl, pf[ks], aco[dt]);
      }
    }
  }

  float inv = 1.0f / l_run;
#pragma unroll
  for (int dt = 0; dt < 4; ++dt) {
    f32x4 o = aco[dt] * inv;
    *(f32x4*)&O[((size_t)b * TSEQ + qg) * DMODEL + h * HDIM + dt * 16 + 4 * g] = o;
  }
}

extern "C" void kernel_launch(void* const* d_in, const int* in_sizes, int n_in,
                              void* d_out, int out_size, void* d_ws, size_t ws_size,
                              hipStream_t stream) {
  const float* query = (const float*)d_in[0];
  const float* key = (const float*)d_in[1];
  const float* value = (const float*)d_in[2];
  const unsigned char* kpm = (const unsigned char*)d_in[3];
  const float* amask = (const float*)d_in[4];
  const float* sf = (const float*)d_in[5];
  const float* Wq = (const float*)d_in[6];
  const float* bq = (const float*)d_in[7];
  const float* Wk = (const float*)d_in[8];
  const float* bk = (const float*)d_in[9];
  const float* Wv = (const float*)d_in[10];
  const float* bv = (const float*)d_in[11];
  const float* Wo = (const float*)d_in[12];
  const float* bo = (const float*)d_in[13];
  const float* alpha = (const float*)d_in[14];
  float* out = (float*)d_out;

  const size_t NEL = (size_t)2 * NHEAD * TSEQ * HDIM;  // 4,194,304 per array
  bf16_t* p = (bf16_t*)d_ws;
  bf16_t* Qh = p;
  bf16_t* Ql = p + NEL;
  bf16_t* Kh = p + 2 * NEL;
  bf16_t* Kl = p + 3 * NEL;
  bf16_t* Vh = p + 4 * NEL;
  bf16_t* Vl = p + 5 * NEL;
  float* Oa = (float*)(p + 6 * NEL);  // 67.1 MB total, same footprint as passing R1

  dim3 gg(16, 32), bb(256);
  gemm_mfma<1><<<gg, bb, 0, stream>>>(query, Wq, bq, Qh, Ql, nullptr);
  gemm_mfma<1><<<gg, bb, 0, stream>>>(key, Wk, bk, Kh, Kl, nullptr);
  gemm_mfma<2><<<gg, bb, 0, stream>>>(value, Wv, bv, Vh, Vl, nullptr);
  dim3 ga(TSEQ / 64, NHEAD, 2);
  attn_mfma<<<ga, bb, 0, stream>>>(Qh, Ql, Kh, Kl, Vh, Vl, amask, kpm, sf, alpha, Oa);
  gemm_mfma<0><<<gg, bb, 0, stream>>>(Oa, Wo, bo, nullptr, nullptr, out);
}

// Round 3
// 397.988 us; speedup vs baseline: 3.9237x; 1.3209x over previous
//
#include <hip/hip_runtime.h>
#include <math.h>

typedef __bf16 bf16_t;
typedef __bf16 bf16x8 __attribute__((ext_vector_type(8)));
typedef __bf16 bf16x4 __attribute__((ext_vector_type(4)));
typedef float  f32x4  __attribute__((ext_vector_type(4)));

#define NHEAD 16
#define HDIM 64
#define DMODEL 1024
#define TSEQ 2048

__device__ __forceinline__ f32x4 mfma16(bf16x8 a, bf16x8 b, f32x4 c) {
  return __builtin_amdgcn_mfma_f32_16x16x32_bf16(a, b, c, 0, 0, 0);
}

// async global->LDS, 16B per lane; lds base must be wave-uniform (HW adds lane*16)
__device__ __forceinline__ void gload16(const bf16_t* g, bf16_t* l) {
  __builtin_amdgcn_global_load_lds((const __attribute__((address_space(1))) void*)g,
                                   (__attribute__((address_space(3))) void*)l, 16, 0, 0);
}

// pack two f32 -> (bf16(hi)<<16)|bf16(lo)
__device__ __forceinline__ unsigned pk2(float lo, float hi) {
  unsigned short a = __builtin_bit_cast(unsigned short, (__bf16)lo);
  unsigned short c = __builtin_bit_cast(unsigned short, (__bf16)hi);
  return ((unsigned)c << 16) | a;
}

// split two f32x4 into hi/lo bf16x8 and store to frag-major LDS slot
__device__ __forceinline__ void cvtstore(f32x4 x0, f32x4 x1, bf16_t* dh, bf16_t* dl, int off) {
  bf16x8 hfr, lfr;
#pragma unroll
  for (int j = 0; j < 4; ++j) {
    float v = x0[j];
    __bf16 hb = (__bf16)v;
    hfr[j] = hb; lfr[j] = (__bf16)(v - (float)hb);
    float w = x1[j];
    __bf16 wb = (__bf16)w;
    hfr[4 + j] = wb; lfr[4 + j] = (__bf16)(w - (float)wb);
  }
  *(bf16x8*)(dh + off) = hfr;
  *(bf16x8*)(dl + off) = lfr;
}

// ---------------- bias table: BM[b][q][k] = alpha*copysign(log1p|df|,df) + amask[q][k] (+ -1e30 if kpm) ----------------
__global__ __launch_bounds__(256)
void build_bias(const float* __restrict__ amask, const unsigned char* __restrict__ kpm,
                const float* __restrict__ sf, const float* __restrict__ alpha_p,
                bf16_t* __restrict__ BM) {
  size_t idx = (size_t)blockIdx.x * 256 + threadIdx.x;   // 1,048,576 threads, 8 k each
  int k8 = (int)(idx & (TSEQ / 8 - 1));
  size_t bq = idx >> 8;                                  // b*T + q
  int b = (int)(bq >> 11);
  int q = (int)(bq & (TSEQ - 1));
  const float sfq = sf[bq];
  const float alpha = *alpha_p;
  const float* sfk = sf + (size_t)b * TSEQ + k8 * 8;
  const float* am  = amask + (size_t)q * TSEQ + k8 * 8;
  const unsigned char* kp = kpm + (size_t)b * TSEQ + k8 * 8;
  bf16x8 o;
#pragma unroll
  for (int j = 0; j < 8; ++j) {
    float df = sfq - sfk[j];
    float v = alpha * copysignf(log1pf(fabsf(df)), df) + am[j];
    if (kp[j]) v = -1.0e30f;
    o[j] = (__bf16)v;
  }
  *(bf16x8*)&BM[idx * 8] = o;
}

// ---------------- GEMM: C = A @ W^T + bias via bf16x3 split MFMA ----------------
// MODE 0: f32 out [M][1024]; MODE 1: bf16 hi/lo head layout [b][h][t][d]; MODE 2: V transposed [b][h][d][t]
template<int MODE>
__global__ __launch_bounds__(256)
void gemm_mfma(const float* __restrict__ A, const float* __restrict__ W,
               const float* __restrict__ bias,
               bf16_t* __restrict__ obh, bf16_t* __restrict__ obl,
               float* __restrict__ of) {
  __shared__ bf16_t AH[8 * 512], AL[8 * 512], WH[4 * 512], WL[4 * 512];
  const int tid = threadIdx.x;
  const int lane = tid & 63;
  const int a15 = lane & 15, g = lane >> 4;
  const int wv = tid >> 6, wm = wv >> 1, wn = wv & 1;
  const int m0 = blockIdx.y * 128, n0 = blockIdx.x * 64;
  constexpr int NI = (MODE == 2) ? 2 : 4;
  constexpr int NJ = (MODE == 2) ? 4 : 2;
  f32x4 acc[NI][NJ] = {};

  const int s0 = tid, s1 = tid + 256;
  const int t0 = s0 >> 6, l0 = s0 & 63;
  const int t1 = s1 >> 6, l1 = s1 & 63;
  const float* pA0 = A + (size_t)(m0 + t0 * 16 + (l0 & 15)) * DMODEL + 8 * (l0 >> 4);
  const float* pA1 = A + (size_t)(m0 + t1 * 16 + (l1 & 15)) * DMODEL + 8 * (l1 >> 4);
  const float* pW  = W + (size_t)(n0 + t0 * 16 + (l0 & 15)) * DMODEL + 8 * (l0 >> 4);

  f32x4 rA0a = *(const f32x4*)pA0, rA0b = *(const f32x4*)(pA0 + 4);
  f32x4 rA1a = *(const f32x4*)pA1, rA1b = *(const f32x4*)(pA1 + 4);
  f32x4 rWa  = *(const f32x4*)pW,  rWb  = *(const f32x4*)(pW + 4);

  for (int k0 = 0; k0 < DMODEL; k0 += 32) {
    __syncthreads();                 // prior compute's LDS reads done
    cvtstore(rA0a, rA0b, AH, AL, s0 * 8);
    cvtstore(rA1a, rA1b, AH, AL, s1 * 8);
    cvtstore(rWa,  rWb,  WH, WL, s0 * 8);
    if (k0 + 32 < DMODEL) {          // prefetch next K-step, overlaps compute below
      pA0 += 32; pA1 += 32; pW += 32;
      rA0a = *(const f32x4*)pA0; rA0b = *(const f32x4*)(pA0 + 4);
      rA1a = *(const f32x4*)pA1; rA1b = *(const f32x4*)(pA1 + 4);
      rWa  = *(const f32x4*)pW;  rWb  = *(const f32x4*)(pW + 4);
    }
    __syncthreads();

    bf16x8 ah[4], al[4], wh[2], wl[2];
#pragma unroll
    for (int i = 0; i < 4; ++i) {
      ah[i] = *(const bf16x8*)&AH[(wm * 4 + i) * 512 + lane * 8];
      al[i] = *(const bf16x8*)&AL[(wm * 4 + i) * 512 + lane * 8];
    }
#pragma unroll
    for (int j = 0; j < 2; ++j) {
      wh[j] = *(const bf16x8*)&WH[(wn * 2 + j) * 512 + lane * 8];
      wl[j] = *(const bf16x8*)&WL[(wn * 2 + j) * 512 + lane * 8];
    }
    if (MODE == 2) {
#pragma unroll
      for (int i = 0; i < 2; ++i)
#pragma unroll
        for (int j = 0; j < 4; ++j) {
          acc[i][j] = mfma16(wh[i], ah[j], acc[i][j]);
          acc[i][j] = mfma16(wh[i], al[j], acc[i][j]);
          acc[i][j] = mfma16(wl[i], ah[j], acc[i][j]);
        }
    } else {
#pragma unroll
      for (int i = 0; i < 4; ++i)
#pragma unroll
        for (int j = 0; j < 2; ++j) {
          acc[i][j] = mfma16(ah[i], wh[j], acc[i][j]);
          acc[i][j] = mfma16(ah[i], wl[j], acc[i][j]);
          acc[i][j] = mfma16(al[i], wh[j], acc[i][j]);
        }
    }
  }

  if (MODE == 0) {
#pragma unroll
    for (int i = 0; i < 4; ++i)
#pragma unroll
      for (int j = 0; j < 2; ++j) {
        int n = n0 + wn * 32 + j * 16 + a15;
        float bs = bias[n];
#pragma unroll
        for (int r = 0; r < 4; ++r) {
          int m = m0 + wm * 64 + i * 16 + 4 * g + r;
          of[(size_t)m * DMODEL + n] = acc[i][j][r] + bs;
        }
      }
  } else if (MODE == 1) {
#pragma unroll
    for (int i = 0; i < 4; ++i)
#pragma unroll
      for (int j = 0; j < 2; ++j) {
        int n = n0 + wn * 32 + j * 16 + a15;
        float bs = bias[n];
        int hh = n >> 6, d = n & 63;
#pragma unroll
        for (int r = 0; r < 4; ++r) {
          int m = m0 + wm * 64 + i * 16 + 4 * g + r;
          int bb = m >> 11, t = m & (TSEQ - 1);
          float v = acc[i][j][r] + bs;
          size_t o = (((size_t)(bb * NHEAD + hh)) * TSEQ + t) * HDIM + d;
          __bf16 hb = (__bf16)v;
          obh[o] = hb;
          obl[o] = (__bf16)(v - (float)hb);
        }
      }
  } else {
#pragma unroll
    for (int i = 0; i < 2; ++i)
#pragma unroll
      for (int j = 0; j < 4; ++j) {
        int m = m0 + wm * 64 + j * 16 + a15;
        int bb = m >> 11, t = m & (TSEQ - 1);
#pragma unroll
        for (int r = 0; r < 4; ++r) {
          int n = n0 + wn * 32 + i * 16 + 4 * g + r;
          float v = acc[i][j][r] + bias[n];
          int hh = n >> 6, d = n & 63;
          size_t o = (((size_t)(bb * NHEAD + hh)) * HDIM + d) * TSEQ + t;
          __bf16 hb = (__bf16)v;
          obh[o] = hb;
          obl[o] = (__bf16)(v - (float)hb);
        }
      }
  }
}

// ---------------- Flash attention, MFMA, double-buffered staging + bias table ----------------
__global__ __launch_bounds__(256)
void attn_mfma(const bf16_t* __restrict__ Qhi, const bf16_t* __restrict__ Qlo,
               const bf16_t* __restrict__ Khi, const bf16_t* __restrict__ Klo,
               const bf16_t* __restrict__ Vth, const bf16_t* __restrict__ Vtl,
               const bf16_t* __restrict__ BMt, float* __restrict__ O) {
  __shared__ bf16_t KH[2][8 * 512], KL[2][8 * 512], VH[2][8 * 512], VL[2][8 * 512];
  const int tid = threadIdx.x;
  const int lane = tid & 63, wv = tid >> 6;
  const int a15 = lane & 15, g = lane >> 4;
  const int b = blockIdx.z, h = blockIdx.y, q0 = blockIdx.x * 64;
  const int bh = b * NHEAD + h;
  const int qg = q0 + wv * 16 + a15;

  const bf16_t* Qh_b = Qhi + ((size_t)bh * TSEQ + qg) * HDIM;
  const bf16_t* Ql_b = Qlo + ((size_t)bh * TSEQ + qg) * HDIM;
  const bf16_t* Kh_b = Khi + (size_t)bh * TSEQ * HDIM;
  const bf16_t* Kl_b = Klo + (size_t)bh * TSEQ * HDIM;
  const bf16_t* Vh_b = Vth + (size_t)bh * HDIM * TSEQ;
  const bf16_t* Vl_b = Vtl + (size_t)bh * HDIM * TSEQ;
  const bf16_t* bmrow = BMt + ((size_t)b * TSEQ + qg) * TSEQ;

  bf16x8 qh[2], ql[2];
  qh[0] = *(const bf16x8*)&Qh_b[8 * g];
  qh[1] = *(const bf16x8*)&Qh_b[32 + 8 * g];
  ql[0] = *(const bf16x8*)&Ql_b[8 * g];
  ql[1] = *(const bf16x8*)&Ql_b[32 + 8 * g];

  f32x4 aco[4] = {};
  float m_run = -3.0e38f, l_run = 0.f;

  auto stage = [&](int k0, int buf) {
#pragma unroll
    for (int c = 0; c < 2; ++c) {
      int sb = wv * 2 + c;
      int ts = sb >> 1, ks = sb & 1;
      size_t ko = (size_t)(k0 + 16 * ts + a15) * HDIM + 32 * ks + 8 * g;
      gload16(Kh_b + ko, &KH[buf][sb * 512]);
      gload16(Kl_b + ko, &KL[buf][sb * 512]);
      size_t vo = (size_t)(16 * ts + a15) * TSEQ + k0 + 32 * ks + 8 * g;
      gload16(Vh_b + vo, &VH[buf][sb * 512]);
      gload16(Vl_b + vo, &VL[buf][sb * 512]);
    }
  };

  stage(0, 0);
  __syncthreads();

  for (int t = 0; t < TSEQ / 64; ++t) {
    const int k0 = t * 64;
    const int cur = t & 1;
    if (t + 1 < TSEQ / 64) stage(k0 + 64, cur ^ 1);   // prefetch next tile (drained at barrier)

    // bias-table loads (hide under MFMA)
    bf16x4 bmv[4];
#pragma unroll
    for (int mt = 0; mt < 4; ++mt) bmv[mt] = *(const bf16x4*)&bmrow[k0 + 16 * mt + 4 * g];

    // S^T frags: D[key][q], 4 key-subtiles of 16
    f32x4 s4[4];
    __builtin_amdgcn_s_setprio(1);
#pragma unroll
    for (int mt = 0; mt < 4; ++mt) {
      bf16x8 k0h = *(const bf16x8*)&KH[cur][(mt * 2 + 0) * 512 + lane * 8];
      bf16x8 k1h = *(const bf16x8*)&KH[cur][(mt * 2 + 1) * 512 + lane * 8];
      bf16x8 k0l = *(const bf16x8*)&KL[cur][(mt * 2 + 0) * 512 + lane * 8];
      bf16x8 k1l = *(const bf16x8*)&KL[cur][(mt * 2 + 1) * 512 + lane * 8];
      f32x4 sa = {};
      sa = mfma16(k0h, qh[0], sa);
      sa = mfma16(k1h, qh[1], sa);
      sa = mfma16(k0h, ql[0], sa);
      sa = mfma16(k1h, ql[1], sa);
      sa = mfma16(k0l, qh[0], sa);
      sa = mfma16(k1l, qh[1], sa);
      s4[mt] = sa;
    }
    __builtin_amdgcn_s_setprio(0);

    // scores: fma with precomputed bias+mask table
#pragma unroll
    for (int mt = 0; mt < 4; ++mt)
#pragma unroll
      for (int r = 0; r < 4; ++r)
        s4[mt][r] = fmaf(s4[mt][r], 0.125f, (float)bmv[mt][r]);

    // online softmax (row = q = a15; partials across lane groups via xor 16,32)
    float tmax = -3.0e38f;
#pragma unroll
    for (int mt = 0; mt < 4; ++mt)
#pragma unroll
      for (int r = 0; r < 4; ++r) tmax = fmaxf(tmax, s4[mt][r]);
    tmax = fmaxf(tmax, __shfl_xor(tmax, 16));
    tmax = fmaxf(tmax, __shfl_xor(tmax, 32));
    float mnew = fmaxf(m_run, tmax);
    float corr = __expf(m_run - mnew);
    float psum = 0.f;
    unsigned pk01[4], pk23[4];
#pragma unroll
    for (int mt = 0; mt < 4; ++mt) {
      float p0 = __expf(s4[mt][0] - mnew);
      float p1 = __expf(s4[mt][1] - mnew);
      float p2 = __expf(s4[mt][2] - mnew);
      float p3 = __expf(s4[mt][3] - mnew);
      psum += (p0 + p1) + (p2 + p3);
      pk01[mt] = pk2(p0, p1);
      pk23[mt] = pk2(p2, p3);
    }
    psum += __shfl_xor(psum, 16);
    psum += __shfl_xor(psum, 32);
    l_run = l_run * corr + psum;
    m_run = mnew;
#pragma unroll
    for (int dt = 0; dt < 4; ++dt) aco[dt] *= corr;

    // P -> B-frag layout: slot (g,j) must hold key 32ks+8g+j of row q=a15
    bf16x8 pf[2];
#pragma unroll
    for (int ks = 0; ks < 2; ++ks) {
      int src0 = a15 + 16 * (2 * (g & 1));
      int src1 = src0 + 16;
      unsigned A0 = __shfl(pk01[2 * ks + 0], src0), A1 = __shfl(pk01[2 * ks + 1], src0);
      unsigned B0 = __shfl(pk23[2 * ks + 0], src0), B1 = __shfl(pk23[2 * ks + 1], src0);
      unsigned C0 = __shfl(pk01[2 * ks + 0], src1), C1 = __shfl(pk01[2 * ks + 1], src1);
      unsigned D0 = __shfl(pk23[2 * ks + 0], src1), D1 = __shfl(pk23[2 * ks + 1], src1);
      bool hi2 = (g >> 1) & 1;
      uint4 wds;
      wds.x = hi2 ? A1 : A0;
      wds.y = hi2 ? B1 : B0;
      wds.z = hi2 ? C1 : C0;
      wds.w = hi2 ? D1 : D0;
      pf[ks] = __builtin_bit_cast(bf16x8, wds);
    }

    // O^T += Vt * P  (V split hi/lo)
    __builtin_amdgcn_s_setprio(1);
#pragma unroll
    for (int dt = 0; dt < 4; ++dt) {
#pragma unroll
      for (int ks = 0; ks < 2; ++ks) {
        bf16x8 vh = *(const bf16x8*)&VH[cur][(dt * 2 + ks) * 512 + lane * 8];
        bf16x8 vl = *(const bf16x8*)&VL[cur][(dt * 2 + ks) * 512 + lane * 8];
        aco[dt] = mfma16(vh, pf[ks], aco[dt]);
        aco[dt] = mfma16(vl, pf[ks], aco[dt]);
      }
    }
    __builtin_amdgcn_s_setprio(0);

    __syncthreads();   // drains prefetch loads; all waves done reading cur
  }

  float inv = 1.0f / l_run;
#pragma unroll
  for (int dt = 0; dt < 4; ++dt) {
    f32x4 o = aco[dt] * inv;
    *(f32x4*)&O[((size_t)b * TSEQ + qg) * DMODEL + h * HDIM + dt * 16 + 4 * g] = o;
  }
}

extern "C" void kernel_launch(void* const* d_in, const int* in_sizes, int n_in,
                              void* d_out, int out_size, void* d_ws, size_t ws_size,
                              hipStream_t stream) {
  const float* query = (const float*)d_in[0];
  const float* key = (const float*)d_in[1];
  const float* value = (const float*)d_in[2];
  const unsigned char* kpm = (const unsigned char*)d_in[3];
  const float* amask = (const float*)d_in[4];
  const float* sf = (const float*)d_in[5];
  const float* Wq = (const float*)d_in[6];
  const float* bq = (const float*)d_in[7];
  const float* Wk = (const float*)d_in[8];
  const float* bk = (const float*)d_in[9];
  const float* Wv = (const float*)d_in[10];
  const float* bv = (const float*)d_in[11];
  const float* Wo = (const float*)d_in[12];
  const float* bo = (const float*)d_in[13];
  const float* alpha = (const float*)d_in[14];
  float* out = (float*)d_out;

  const size_t NEL = (size_t)2 * NHEAD * TSEQ * HDIM;  // 4,194,304 per bf16 array
  bf16_t* p = (bf16_t*)d_ws;
  bf16_t* Qh = p;
  bf16_t* Ql = p + NEL;
  bf16_t* Kh = p + 2 * NEL;
  bf16_t* Kl = p + 3 * NEL;
  bf16_t* Vh = p + 4 * NEL;
  bf16_t* Vl = p + 5 * NEL;
  float* Oa = (float*)(p + 6 * NEL);                    // 16.8 MB
  bf16_t* BMt = (bf16_t*)(Oa + (size_t)4096 * DMODEL);  // 16.8 MB  (total 80 MiB)

  dim3 bb(256);
  build_bias<<<dim3(4096), bb, 0, stream>>>(amask, kpm, sf, alpha, BMt);

  dim3 gg(16, 32);
  gemm_mfma<1><<<gg, bb, 0, stream>>>(query, Wq, bq, Qh, Ql, nullptr);
  gemm_mfma<1><<<gg, bb, 0, stream>>>(key, Wk, bk, Kh, Kl, nullptr);
  gemm_mfma<2><<<gg, bb, 0, stream>>>(value, Wv, bv, Vh, Vl, nullptr);
  dim3 ga(TSEQ / 64, NHEAD, 2);
  attn_mfma<<<ga, bb, 0, stream>>>(Qh, Ql, Kh, Kl, Vh, Vl, BMt, Oa);
  gemm_mfma<0><<<gg, bb, 0, stream>>>(Oa, Wo, bo, nullptr, nullptr, out);
}